// Round 9
// baseline (464.221 us; speedup 1.0000x reference)
//
#include <hip/hip_runtime.h>

// PartialProductAccumulator: 54-step ripple add with dropped carry-out
// == sum of 54 partial products mod 2^108.
// FUSED single kernel (best measured config, R7 = 460.4 us):
//   phase 1: per-bit-column popcount (exact in fp32, max 54), nontemporal
//            streamed from HBM (R5 A/B: removing nt cost +29us), depth-4
//            register pipeline, 1 float4 column per thread.
//   phase 2: counts -> LDS (stride 109, conflict-free), 16 threads/block do
//            the serial 108-step carry (t = cnt + c; bit = t&1; c = t>>1),
//            all 432 threads write the output tile contiguously (NORMAL
//            store -- R8 A/B: nt store was +3us).
// Block = 432 threads = 16 rows x 27 float4 (rows never straddle blocks);
// 1024 blocks = 4 blocks/CU = 28 waves/CU.
//
// Structural ceiling note: phase-1 read stream sustains ~3.9-4.3 TB/s; depth,
// burst size, and occupancy changes are all neutral => pinned at per-CU
// outstanding-read capacity (~45 x 128B lines in flight @ ~900 cy HBM
// latency), not at the 6.3 TB/s copy ceiling.

#define N_PP   54
#define BITS   108
#define BATCH  16384
#define ROW_F4 (BITS / 4)                    // 27 float4 per row
#define PLANE_F4 ((size_t)BATCH * ROW_F4)    // 442368 float4 per p-plane
#define ROWS_PB 16                           // batch rows per block
#define TPB     (ROWS_PB * ROW_F4)           // 432 threads (7 waves)

typedef float vf4 __attribute__((ext_vector_type(4)));

__global__ __launch_bounds__(TPB)
void ppacc_fused(const vf4* __restrict__ pps, vf4* __restrict__ out) {
    __shared__ float counts[ROWS_PB][BITS + 1];   // stride 109 = 13 mod 32

    const int tid = threadIdx.x;
    const size_t i0 = (size_t)blockIdx.x * TPB + tid;
    const vf4* p = pps + i0;

    // ---- phase 1: column popcount, depth-4 nt pipeline ----
    vf4 acc = (vf4)(0.f);

    vf4 v0 = __builtin_nontemporal_load(p + 0 * PLANE_F4);
    vf4 v1 = __builtin_nontemporal_load(p + 1 * PLANE_F4);
    vf4 v2 = __builtin_nontemporal_load(p + 2 * PLANE_F4);
    vf4 v3 = __builtin_nontemporal_load(p + 3 * PLANE_F4);

    for (int q = 4; q + 4 <= N_PP - 2; q += 4) {      // planes 4..51
        const vf4* pq = p + (size_t)q * PLANE_F4;
        vf4 n0 = __builtin_nontemporal_load(pq + 0 * PLANE_F4);
        vf4 n1 = __builtin_nontemporal_load(pq + 1 * PLANE_F4);
        vf4 n2 = __builtin_nontemporal_load(pq + 2 * PLANE_F4);
        vf4 n3 = __builtin_nontemporal_load(pq + 3 * PLANE_F4);
        acc += v0; acc += v1; acc += v2; acc += v3;
        v0 = n0; v1 = n1; v2 = n2; v3 = n3;
    }
    vf4 e0 = __builtin_nontemporal_load(p + (size_t)(N_PP - 2) * PLANE_F4);
    vf4 e1 = __builtin_nontemporal_load(p + (size_t)(N_PP - 1) * PLANE_F4);
    acc += v0; acc += v1; acc += v2; acc += v3;
    acc += e0; acc += e1;

    // ---- phase 2: carry propagation through LDS ----
    {
        const int row = tid / ROW_F4;                 // 0..15
        const int bit = (tid % ROW_F4) * 4;
        counts[row][bit + 0] = acc.x;
        counts[row][bit + 1] = acc.y;
        counts[row][bit + 2] = acc.z;
        counts[row][bit + 3] = acc.w;
    }
    __syncthreads();

    if (tid < ROWS_PB) {
        int c = 0;
#pragma unroll
        for (int i = 0; i < BITS; ++i) {
            const int t = (int)counts[tid][i] + c;
            counts[tid][i] = (float)(t & 1);
            c = t >> 1;                               // carry out of bit 107 dropped
        }
    }
    __syncthreads();

    {
        const int row = tid / ROW_F4;
        const int bit = (tid % ROW_F4) * 4;
        vf4 v;
        v.x = counts[row][bit + 0];
        v.y = counts[row][bit + 1];
        v.z = counts[row][bit + 2];
        v.w = counts[row][bit + 3];
        out[i0] = v;
    }
}

extern "C" void kernel_launch(void* const* d_in, const int* in_sizes, int n_in,
                              void* d_out, int out_size, void* d_ws, size_t ws_size,
                              hipStream_t stream) {
    const vf4* pps = (const vf4*)d_in[0];
    vf4* out = (vf4*)d_out;
    ppacc_fused<<<(int)(PLANE_F4 / TPB), TPB, 0, stream>>>(pps, out);   // 1024 blocks
}